// Round 5
// baseline (268.777 us; speedup 1.0000x reference)
//
#include <hip/hip_runtime.h>
#include <stdint.h>

typedef unsigned int uint;
typedef unsigned short ushort;
typedef __attribute__((ext_vector_type(8))) short short8;
typedef __attribute__((ext_vector_type(16))) float floatx16;

#define MEG (1024u * 1024u)

// ---------- helpers ----------
__device__ inline ushort f2b(float f) {           // fp32 -> bf16 RNE
  union { float f; uint u; } c; c.f = f;
  uint u = c.u;
  u = (u + 0x7fffu + ((u >> 16) & 1u)) >> 16;
  return (ushort)u;
}
__device__ inline float b2f(ushort u) {
  union { uint i; float f; } c; c.i = ((uint)u) << 16; return c.f;
}

__device__ inline void gl_lds16(const ushort* g, ushort* l) {
  // async global->LDS, 16B/lane; LDS dest = wave-uniform base + lane*16
  __builtin_amdgcn_global_load_lds(
      (const __attribute__((address_space(1))) void*)g,
      (__attribute__((address_space(3))) void*)l, 16, 0, 0);
}

// ---------------------------------------------------------------------------
// fp32->bf16 convert (x: 4096 blocks, W: 3x512 blocks).
// ---------------------------------------------------------------------------
__global__ __launch_bounds__(256) void cvt_all(
    const float* __restrict__ x,  const float* __restrict__ wq,
    const float* __restrict__ wk, const float* __restrict__ wv,
    ushort* __restrict__ xb, ushort* __restrict__ wb)
{
  const int b = blockIdx.x;
  const float* s; ushort* d; int i;
  if (b < 4096) {
    s = x; d = xb; i = b * 256 + threadIdx.x;
  } else {
    int t = b - 4096;
    int wsel = t >> 9;
    s = (wsel == 0) ? wq : (wsel == 1) ? wk : wv;
    d = wb + (size_t)wsel * MEG;
    i = (t & 511) * 256 + threadIdx.x;
  }
  float4 a = ((const float4*)s)[i * 2];
  float4 c = ((const float4*)s)[i * 2 + 1];
  short8 v;
  v[0] = (short)f2b(a.x); v[1] = (short)f2b(a.y);
  v[2] = (short)f2b(a.z); v[3] = (short)f2b(a.w);
  v[4] = (short)f2b(c.x); v[5] = (short)f2b(c.y);
  v[6] = (short)f2b(c.z); v[7] = (short)f2b(c.w);
  ((short8*)d)[i] = v;
}

// ---------------------------------------------------------------------------
// Shared GEMM-BT core:  C[m][n] = f( sum_k A[m][k] * B[n][k] )
// 128 x BN block tile, 256 thr = 2x2 waves, MFMA 32x32x16 (floatx16 acc).
// R16: BK=32 DOUBLE-BUFFERED, ONE barrier per K-tile, stage-issue at tile
// TOP (R13 schedule) at R3 occupancy (LDS 2x16KB=32KB -> 4 blocks/CU).
//   R3 did {sync; STAGE; sync; compute}: the drain immediately follows the
//   issue -> full HBM latency exposed per tile, hidden only by other blocks
//   (730 TF). R13 issued early but at 256^2/1-block/CU (610 TF). This
//   combines both: drain at tile end waits on loads issued one full tile
//   earlier (hidden under compute) AND 4 blocks/CU of TLP remain.
//   Race-freedom: STAGE(t+1) into slot s^1 issues after the barrier that
//   ends tile t-1 (whose reads of s^1 drained at that barrier: WAW safe).
//   RAW: tile t's reads follow the t-1-end barrier whose implicit vmcnt(0)
//   drained the loads issued at the top of t-1.
// Swizzle (64B rows, 4x16B chunks): chunk' = chunk ^ ((row>>1)&3) — same
// 4-lanes-per-16B-slot spread as the R5-proven BK=64 variant (conflicts 0).
// Pre-applied on the GLOBAL source (gl_lds dest linear, rule 21), undone on
// ds_read. No XCD swizzle (R6 regressed). BN=64 regressed (R15): MFMA:LDS
// ratio beats occupancy on this core.
// MODE 0 (BN=128): fused-QKV split (n<2048 -> Q/K bf16 row-major, else Vt^T)
// MODE 1 (BN=128): p = exp2(s*scale) bf16 out; per-block partial row sums
//                  plain-stored to Lp[(nb*2+nw)][bz][2048]  (R14: no atomics;
//                  |s|*scale bounded ~8 so no max subtraction, fp32-safe)
// MODE 2 (BN=128): fp32 out * 1/rowsum; rowsum = sum of 32 Lp partials
//                  (cooperative prologue into LDS Linv[128])
// ---------------------------------------------------------------------------
template <int MODE, int BN>
__device__ __forceinline__ void gemm_core(
    const ushort* __restrict__ A, int lda, size_t sA,
    const ushort* __restrict__ B, int ldb, size_t sB,
    void* __restrict__ C, int ldc, size_t sC,
    int K, float scale, float* __restrict__ Lsum)
{
  constexpr int NJ = BN / 64;          // n-frags per wave (2)
  constexpr int BI = BN / 64;          // B stage issues per tile (2)
  constexpr int ASLOT = 128 * 32;      // ushorts per A slot (8 KiB)
  constexpr int BSLOT = BN * 32;
  __shared__ ushort As[2 * ASLOT];     // 16 KiB
  __shared__ ushort Bs[2 * BSLOT];     // 16 KiB
  __shared__ float Linv[(MODE == 2) ? 128 : 1];

  const int tid = threadIdx.x;
  const int bz  = blockIdx.z;
  A += (size_t)bz * sA;
  B += (size_t)bz * sB;

  const int m0 = blockIdx.y * 128;
  const int n0 = blockIdx.x * BN;

  const int lane = tid & 63;
  const int w    = tid >> 6;
  const int l32  = lane & 31;
  const int lh   = lane >> 5;          // 0/1 -> k-half of the 16-k step
  const int mw   = w >> 1;
  const int nw   = w & 1;

  // ---- PV prologue: reduce 32 Lp partials per row -> Linv (R14) ----
  if constexpr (MODE == 2) {
    if (tid < 128) {
      float s = 0.f;
#pragma unroll
      for (int p = 0; p < 32; ++p)
        s += Lsum[((size_t)p * gridDim.z + bz) * 2048 + m0 + tid];
      Linv[tid] = 1.0f / s;
    }
    // prologue __syncthreads publishes Linv before any use
  }

  // ---- staging pointers: 64 rows/issue, 4 lanes x 16B per 64B row ----
  const int srow = tid >> 2;           // 0..63
  const int sch  = tid & 3;
  const ushort* agp[2];
  const ushort* bgp[BI];
#pragma unroll
  for (int q = 0; q < 2; ++q) {
    int r = q * 64 + srow;
    agp[q] = A + (size_t)(m0 + r) * lda + ((sch ^ ((r >> 1) & 3)) * 8);
  }
#pragma unroll
  for (int q = 0; q < BI; ++q) {
    int r = q * 64 + srow;
    bgp[q] = B + (size_t)(n0 + r) * ldb + ((sch ^ ((r >> 1) & 3)) * 8);
  }

  // ---- fragment rows + swizzle keys (loop-invariant) ----
  int arow[2], aswz[2], brow[NJ], bswz[NJ];
#pragma unroll
  for (int t = 0; t < 2; ++t) {
    arow[t] = mw * 64 + t * 32 + l32;
    aswz[t] = (arow[t] >> 1) & 3;
  }
#pragma unroll
  for (int t = 0; t < NJ; ++t) {
    brow[t] = nw * (BN / 2) + t * 32 + l32;
    bswz[t] = (brow[t] >> 1) & 3;
  }

  floatx16 acc[2][NJ];
#pragma unroll
  for (int i = 0; i < 2; ++i)
#pragma unroll
    for (int j = 0; j < NJ; ++j)
#pragma unroll
      for (int r = 0; r < 16; ++r) acc[i][j][r] = 0.f;

  const int nt = K / 32;

#define STAGE(slot)                                                       \
  {                                                                       \
    ushort* Ad = &As[(slot) * ASLOT];                                     \
    ushort* Bd = &Bs[(slot) * BSLOT];                                     \
    _Pragma("unroll")                                                     \
    for (int q = 0; q < 2; ++q) {                                         \
      gl_lds16(agp[q], Ad + (q * 64 + w * 16) * 32); agp[q] += 32;        \
    }                                                                     \
    _Pragma("unroll")                                                     \
    for (int q = 0; q < BI; ++q) {                                        \
      gl_lds16(bgp[q], Bd + (q * 64 + w * 16) * 32); bgp[q] += 32;        \
    }                                                                     \
  }

  // prologue: stage tile 0; the syncthreads drain makes it resident
  STAGE(0);
  __syncthreads();

  for (int t = 0; t < nt; ++t) {
    const ushort* At = &As[(t & 1) * ASLOT];
    const ushort* Bt = &Bs[(t & 1) * BSLOT];
    if (t + 1 < nt) STAGE((t + 1) & 1);   // issue EARLY: the drain at tile
                                          // end waits on tile-old loads
#pragma unroll
    for (int s = 0; s < 2; ++s) {         // 2 k-steps of 16
      short8 af[2], bf[NJ];
#pragma unroll
      for (int i = 0; i < 2; ++i)
        af[i] = *(const short8*)&At[arow[i] * 32 + (((s * 2 + lh) ^ aswz[i]) * 8)];
#pragma unroll
      for (int j = 0; j < NJ; ++j)
        bf[j] = *(const short8*)&Bt[brow[j] * 32 + (((s * 2 + lh) ^ bswz[j]) * 8)];
#pragma unroll
      for (int i = 0; i < 2; ++i)
#pragma unroll
        for (int j = 0; j < NJ; ++j)
          acc[i][j] = __builtin_amdgcn_mfma_f32_32x32x16_bf16(
              af[i], bf[j], acc[i][j], 0, 0, 0);
    }
    __syncthreads();   // vmcnt(0)+lgkmcnt(0)+barrier: tile t+1 ready, slot
                       // t&1 free for overwrite next iteration
  }
#undef STAGE

  // ---- epilogue; C/D (32x32): col = lane&31, row = (reg&3)+8*(reg>>2)+4*lh
  if constexpr (MODE == 0) {   // fused-QKV split
#pragma unroll
    for (int i = 0; i < 2; ++i)
#pragma unroll
      for (int j = 0; j < NJ; ++j) {
        const int mbase = m0 + mw * 64 + i * 32 + 4 * lh;
        const int ng    = n0 + nw * (BN / 2) + j * 32 + l32;
        if (ng < 2048) {
          // Qb @ C, Kb @ C + 8M elems
          ushort* dst = (ushort*)C + (size_t)(ng >> 10) * (8u * MEG);
          const int nn = ng & 1023;
#pragma unroll
          for (int g = 0; g < 4; ++g)
#pragma unroll
            for (int r = 0; r < 4; ++r)
              dst[(size_t)(mbase + 8 * g + r) * 1024 + nn] =
                  f2b(acc[i][j][4 * g + r]);
        } else {
          // Vt @ C + 16M elems, transposed [1024][8192]
          ushort* Vo = (ushort*)C + (size_t)16 * MEG;
#pragma unroll
          for (int g = 0; g < 4; ++g) {
            uint lo = (uint)f2b(acc[i][j][4 * g + 0]) |
                      ((uint)f2b(acc[i][j][4 * g + 1]) << 16);
            uint hi = (uint)f2b(acc[i][j][4 * g + 2]) |
                      ((uint)f2b(acc[i][j][4 * g + 3]) << 16);
            *(uint2*)&Vo[(size_t)(ng - 2048) * 8192 + mbase + 8 * g] =
                make_uint2(lo, hi);
          }
        }
      }
  } else if constexpr (MODE == 1) {   // p = exp2(s*scale), partials -> Lp
    ushort* Cb = (ushort*)C + (size_t)bz * sC;
    float* Lp = Lsum + ((size_t)(blockIdx.x * 2 + nw) * gridDim.z + bz) * 2048;
    const int ng0 = n0 + nw * (BN / 2) + l32;
#pragma unroll
    for (int i = 0; i < 2; ++i) {
      const int mbase = m0 + mw * 64 + i * 32 + 4 * lh;
#pragma unroll
      for (int g = 0; g < 4; ++g)
#pragma unroll
        for (int r = 0; r < 4; ++r) {
          const int mg = mbase + 8 * g + r;
          float p0 = exp2f(acc[i][0][4 * g + r] * scale);
          float p1 = exp2f(acc[i][NJ - 1][4 * g + r] * scale);
          ushort u0 = f2b(p0), u1 = f2b(p1);
          Cb[(size_t)mg * ldc + ng0]      = u0;
          Cb[(size_t)mg * ldc + ng0 + 32] = u1;
          float ps = b2f(u0) + b2f(u1);   // sum of *rounded* p (matches PV)
#pragma unroll
          for (int d = 1; d < 32; d <<= 1) ps += __shfl_xor(ps, d);
          if (l32 == 0) Lp[mg] = ps;      // plain store: (nb,nw) unique slot
        }
    }
  } else {                    // MODE 2: normalized fp32 output
    float* Cb = (float*)C + (size_t)bz * sC;
#pragma unroll
    for (int i = 0; i < 2; ++i) {
      const int mbase = m0 + mw * 64 + i * 32 + 4 * lh;
#pragma unroll
      for (int g = 0; g < 4; ++g)
#pragma unroll
        for (int r = 0; r < 4; ++r) {
          const int mg = mbase + 8 * g + r;
          const float inv = Linv[mg - m0];
#pragma unroll
          for (int j = 0; j < NJ; ++j) {
            const int ng = n0 + nw * (BN / 2) + j * 32 + l32;
            Cb[(size_t)mg * ldc + ng] = acc[i][j][4 * g + r] * inv;
          }
        }
    }
  }
}

// ---- distinct symbols per stage (counter attribution) ----
// (256,4): 64 VGPR + 64 AGPR = 128 unified = the 16-wave/CU boundary (m69);
// LDS 32KB/block -> 4 blocks/CU preserved under the R16 double-buffer.
__global__ __launch_bounds__(256, 4) void gemm_qkv(
    const ushort* __restrict__ A, int lda, size_t sA,
    const ushort* __restrict__ B, int ldb, size_t sB,
    void* __restrict__ C, int ldc, size_t sC, int K, float scale,
    float* __restrict__ Lsum) {
  gemm_core<0, 128>(A, lda, sA, B, ldb, sB, C, ldc, sC, K, scale, Lsum);
}
// S grid is exactly 1024 blocks = 4/CU x 256 CU -> one resident round.
__global__ __launch_bounds__(256, 4) void gemm_s(
    const ushort* __restrict__ A, int lda, size_t sA,
    const ushort* __restrict__ B, int ldb, size_t sB,
    void* __restrict__ C, int ldc, size_t sC, int K, float scale,
    float* __restrict__ Lsum) {
  gemm_core<1, 128>(A, lda, sA, B, ldb, sB, C, ldc, sC, K, scale, Lsum);
}
// PV back to BN=128 (R15's BN=64 regressed ~11us). 512 blocks = 2/CU; the
// R16 issue-early schedule gives PV the intra-block latency hiding that its
// low block count can't provide via TLP.
__global__ __launch_bounds__(256, 4) void gemm_pv(
    const ushort* __restrict__ A, int lda, size_t sA,
    const ushort* __restrict__ B, int ldb, size_t sB,
    void* __restrict__ C, int ldc, size_t sC, int K, float scale,
    float* __restrict__ Lsum) {
  gemm_core<2, 128>(A, lda, sA, B, ldb, sB, C, ldc, sC, K, scale, Lsum);
}

// ---------------------------------------------------------------------------
// ws layout (ushort elems), total 81 MiB  (proven ws >= 90.2 MB):
//   Qb @ 0      [8192][1024]   (16 MiB)
//   Kb @ 8M     [8192][1024]   (16 MiB)
//   Vt @ 16M    [1024][8192]   (16 MiB)
//   xb @ 24M    [8192][1024]   (16 MiB)  -- dead after QKV
//   Wb @ 32M    [3072][1024]   ( 6 MiB)  -- dead after QKV
//   P  @ 24M    [4][2048][2048] (32 MiB) -- OVERLAYS xb+Wb (both dead)
//   Lp @ 40M    fp32 [32][4][2048] ( 1 MiB)  -- per-(nb,nw) partial row sums
// ---------------------------------------------------------------------------
extern "C" void kernel_launch(void* const* d_in, const int* in_sizes, int n_in,
                              void* d_out, int out_size, void* d_ws, size_t ws_size,
                              hipStream_t stream) {
  const float* x  = (const float*)d_in[0];
  const float* Wq = (const float*)d_in[1];
  const float* Wk = (const float*)d_in[2];
  const float* Wv = (const float*)d_in[3];
  float* outp = (float*)d_out;

  const float SCALE = 1.4426950408889634f / 32.0f;   // log2(e)/sqrt(1024)

  ushort* W0 = (ushort*)d_ws;
  ushort* Qb = W0;
  ushort* Kb = W0 + (size_t)8 * MEG;
  ushort* Vt = W0 + (size_t)16 * MEG;
  ushort* xb = W0 + (size_t)24 * MEG;
  ushort* Wb = W0 + (size_t)32 * MEG;
  ushort* Pb = W0 + (size_t)24 * MEG;            // overlays xb/Wb after QKV

  // full: P[4] (32 MiB) + Lp 32*4*2048*4B (1 MiB)
  const size_t NEED_FULL = ((size_t)40 * MEG) * 2 + (size_t)32 * 4 * 2048 * 4;
  const bool full = ws_size >= NEED_FULL;
  float* Lp = full ? (float*)(W0 + (size_t)40 * MEG)
                   : (float*)(W0 + (size_t)28 * MEG);  // per-batch: P is 8 MiB

  cvt_all<<<5632, 256, 0, stream>>>(x, Wq, Wk, Wv, xb, Wb);

  // fused QKV projection: [8192x1024] x [3072x1024]^T, split epilogue
  gemm_qkv<<<dim3(24, 64, 1), 256, 0, stream>>>(
      xb, 1024, 0, Wb, 1024, 0, Qb, 1024, 0, 1024, 1.f, nullptr);

  if (full) {
    gemm_s<<<dim3(16, 16, 4), 256, 0, stream>>>(
        Qb, 1024, (size_t)2048 * 1024, Kb, 1024, (size_t)2048 * 1024,
        Pb, 2048, (size_t)2048 * 2048, 1024, SCALE, Lp);
    gemm_pv<<<dim3(8, 16, 4), 256, 0, stream>>>(
        Pb, 2048, (size_t)2048 * 2048, Vt, 8192, 2048,
        outp, 1024, (size_t)2048 * 1024, 2048, 1.f, Lp);
  } else {
    // per-batch fallback (P single batch @24M, Lp @28M; no memset needed —
    // every Lp slot is plain-stored exactly once per S launch)
    for (int b = 0; b < 4; ++b) {
      gemm_s<<<dim3(16, 16, 1), 256, 0, stream>>>(
          Qb + (size_t)b * 2048 * 1024, 1024, 0,
          Kb + (size_t)b * 2048 * 1024, 1024, 0,
          Pb, 2048, 0, 1024, SCALE, Lp);
      gemm_pv<<<dim3(8, 16, 1), 256, 0, stream>>>(
          Pb, 2048, 0, Vt + (size_t)b * 2048, 8192, 0,
          outp + (size_t)b * 2048 * 1024, 1024, 0, 2048, 1.f, Lp);
    }
  }
}